// Round 1
// baseline (511.336 us; speedup 1.0000x reference)
//
#include <hip/hip_runtime.h>

// ---------------------------------------------------------------------------
// CustomCrossAttentionMinimal on MI355X (gfx950)
// b=16, i=4096, j=77, qd=320, cd=768, H=8, DH=40, inner=320
// ---------------------------------------------------------------------------

typedef _Float16 vh8 __attribute__((ext_vector_type(8)));
typedef _Float16 vh4 __attribute__((ext_vector_type(4)));
typedef float    vf4 __attribute__((ext_vector_type(4)));

#define NEGBIG  (-3.4028235e38f)
#define SCALE_F 0.15811388300841897f   // 40^-0.5

__device__ __forceinline__ vh8 h8zero() {
  vh8 v;
#pragma unroll
  for (int i = 0; i < 8; ++i) v[i] = (_Float16)0.f;
  return v;
}
__device__ __forceinline__ vf4 f4zero() {
  vf4 v;
#pragma unroll
  for (int i = 0; i < 4; ++i) v[i] = 0.f;
  return v;
}
__device__ __forceinline__ float gelu_exact(float x) {
  return 0.5f * x * (1.0f + erff(x * 0.70710678118654752f));
}

// ---------------------------------------------------------------------------
// Generic fp16-MFMA GEMM:  C[M,N] = A[M,K] @ W[K,N] (+bias)
// A: fp32 or fp16 row-major; W fp32 row-major; C fp32 or fp16.
// BM=128, BN=80, BK=64, 256 threads (4 waves), XOR-swizzled LDS.
// ---------------------------------------------------------------------------
template<bool A_HALF, bool BIAS, bool OUT_F32>
__global__ __launch_bounds__(256) void gemm_kernel(
    const void* __restrict__ Ap, const float* __restrict__ W,
    const float* __restrict__ bias, void* __restrict__ Cp,
    int M, int N, int K)
{
  __shared__ _Float16 As[128 * 64];   // [row][k], pitch 128B, XOR (row&7)<<4
  __shared__ _Float16 Bs[80 * 64];    // BsT: [n][k], pitch 128B, XOR (n&7)<<4
  const int t    = threadIdx.x;
  const int lane = t & 63;
  const int wave = t >> 6;
  const int m0 = blockIdx.x * 128;
  const int n0 = blockIdx.y * 80;

  vf4 acc[2][5];
#pragma unroll
  for (int a = 0; a < 2; ++a)
#pragma unroll
    for (int bq = 0; bq < 5; ++bq) acc[a][bq] = f4zero();

  for (int k0 = 0; k0 < K; k0 += 64) {
    __syncthreads();
    // stage A tile (128x64), convert to fp16
#pragma unroll
    for (int p = 0; p < 8; ++p) {
      int idx = t + p * 256;         // 0..2047
      int row = idx >> 4;
      int g4  = idx & 15;
      int m   = m0 + row;
      float v0 = 0.f, v1 = 0.f, v2 = 0.f, v3 = 0.f;
      if (m < M) {
        if (A_HALF) {
          const _Float16* ap = (const _Float16*)Ap + (size_t)m * K + k0 + g4 * 4;
          vh4 hv = *(const vh4*)ap;
          v0 = (float)hv[0]; v1 = (float)hv[1]; v2 = (float)hv[2]; v3 = (float)hv[3];
        } else {
          const float* ap = (const float*)Ap + (size_t)m * K + k0 + g4 * 4;
          float4 f = *(const float4*)ap;
          v0 = f.x; v1 = f.y; v2 = f.z; v3 = f.w;
        }
      }
      vh4 hw;
      hw[0] = (_Float16)v0; hw[1] = (_Float16)v1; hw[2] = (_Float16)v2; hw[3] = (_Float16)v3;
      unsigned byte = (unsigned)(row * 128 + g4 * 8) ^ (unsigned)((row & 7) << 4);
      *(vh4*)((char*)As + byte) = hw;
    }
    // stage B tile transposed: BsT[n][kk]
#pragma unroll
    for (int p = 0; p < 20; ++p) {
      int idx = t + p * 256;         // 0..5119
      int kk = idx / 80;
      int n  = idx - kk * 80;
      float wv = W[(size_t)(k0 + kk) * N + n0 + n];
      unsigned byte = (unsigned)(n * 128 + kk * 2) ^ (unsigned)((n & 7) << 4);
      *(_Float16*)((char*)Bs + byte) = (_Float16)wv;
    }
    __syncthreads();
#pragma unroll
    for (int ks = 0; ks < 2; ++ks) {
      vh8 av[2], bv[5];
#pragma unroll
      for (int mt = 0; mt < 2; ++mt) {
        int row = wave * 32 + mt * 16 + (lane & 15);
        unsigned byte = (unsigned)(row * 128 + (ks * 32 + (lane >> 4) * 8) * 2) ^ (unsigned)((row & 7) << 4);
        av[mt] = *(const vh8*)((const char*)As + byte);
      }
#pragma unroll
      for (int nt = 0; nt < 5; ++nt) {
        int n = nt * 16 + (lane & 15);
        unsigned byte = (unsigned)(n * 128 + (ks * 32 + (lane >> 4) * 8) * 2) ^ (unsigned)((n & 7) << 4);
        bv[nt] = *(const vh8*)((const char*)Bs + byte);
      }
#pragma unroll
      for (int mt = 0; mt < 2; ++mt)
#pragma unroll
        for (int nt = 0; nt < 5; ++nt)
          acc[mt][nt] = __builtin_amdgcn_mfma_f32_16x16x32_f16(av[mt], bv[nt], acc[mt][nt], 0, 0, 0);
    }
  }
  // epilogue: D row=(l>>4)*4+r, col=l&15
#pragma unroll
  for (int mt = 0; mt < 2; ++mt)
#pragma unroll
    for (int nt = 0; nt < 5; ++nt) {
      int n = n0 + nt * 16 + (lane & 15);
#pragma unroll
      for (int r = 0; r < 4; ++r) {
        int m = m0 + wave * 32 + mt * 16 + (lane >> 4) * 4 + r;
        if (m < M) {
          float v = acc[mt][nt][r];
          if (BIAS) v += bias[n];
          if (OUT_F32) ((float*)Cp)[(size_t)m * N + n] = v;
          else ((_Float16*)Cp)[(size_t)m * N + n] = (_Float16)v;
        }
      }
    }
}

// ---------------------------------------------------------------------------
// Progress classifier: pc[b][h][2] softmax
// ---------------------------------------------------------------------------
__global__ __launch_bounds__(256) void classifier_kernel(
    const float* __restrict__ progress,
    const float* __restrict__ emb1, const float* __restrict__ emb2,
    const float* __restrict__ Wc1, const float* __restrict__ bc1,
    const float* __restrict__ Wc2, const float* __restrict__ bc2,
    float* __restrict__ pcb)
{
  __shared__ float g[512];
  __shared__ float h1[512];
  __shared__ float lg[16];
  const int b = blockIdx.x;
  const int t = threadIdx.x;

  float pr = progress[b];
  int xstep = (int)rintf(pr * 1000.0f);          // round-half-even matches jnp.round
  if (xstep > 999) xstep = 999;
  int a = xstep / 20;
  int r = xstep - a * 20;

  for (int d = t; d < 512; d += 256) {
    float e = emb1[a * 512 + d] + emb2[r * 512 + d];
    g[d] = gelu_exact(e);
  }
  __syncthreads();
  for (int n = t; n < 512; n += 256) {
    float acc = bc1[n];
    for (int d = 0; d < 512; ++d) acc = fmaf(g[d], Wc1[d * 512 + n], acc);
    h1[n] = gelu_exact(acc);
  }
  __syncthreads();
  if (t < 16) {
    float acc = bc2[t];
    for (int d = 0; d < 512; ++d) acc = fmaf(h1[d], Wc2[d * 16 + t], acc);
    lg[t] = acc;
  }
  __syncthreads();
  if (t < 8) {
    float a0 = lg[2 * t], a1 = lg[2 * t + 1];
    float mx = fmaxf(a0, a1);
    float e0 = __expf(a0 - mx), e1 = __expf(a1 - mx);
    float inv = 1.0f / (e0 + e1);
    pcb[(b * 8 + t) * 2 + 0] = e0 * inv;
    pcb[(b * 8 + t) * 2 + 1] = e1 * inv;
  }
}

// ---------------------------------------------------------------------------
// Pass 1: masked Sum / SumSq of sim (fp64), per-block partials.
// Grid (64 itiles, 16 b), 256 thr. Recomputes sim via MFMA from q,k fp16.
// ---------------------------------------------------------------------------
__global__ __launch_bounds__(256) void std_kernel(
    const _Float16* __restrict__ q, const _Float16* __restrict__ kf,
    const int* __restrict__ ctypes, double* __restrict__ partials)
{
  __shared__ _Float16 kbuf[80 * 64];      // [j][d], pitch 128B, XOR (j&7)<<4
  __shared__ unsigned char m2v[96];
  __shared__ double redS[256];
  __shared__ double redS2[256];
  const int t = threadIdx.x, lane = t & 63, wave = t >> 6;
  const int it = blockIdx.x, b = blockIdx.y;
  const int i0 = it * 64;

  if (t < 96) {
    int j = t;
    int ct = (j < 77) ? ctypes[b * 77 + j] : -1;
    m2v[j] = (j < 77 && ct >= 2) ? 1 : 0;
  }
  double S = 0.0, S2 = 0.0;

  for (int h = 0; h < 8; ++h) {
    __syncthreads();
#pragma unroll
    for (int p = 0; p < 3; ++p) {
      int idx = t + p * 256;
      if (idx < 640) {
        int j = idx >> 3, c8 = idx & 7, d0 = c8 * 8;
        vh8 val = h8zero();
        if (j < 77 && d0 < 40)
          val = *(const vh8*)(kf + (size_t)(b * 77 + j) * 320 + h * 40 + d0);
        unsigned byte = (unsigned)(j * 128 + d0 * 2) ^ (unsigned)((j & 7) << 4);
        *(vh8*)((char*)kbuf + byte) = val;
      }
    }
    __syncthreads();
    int qrow = b * 4096 + i0 + wave * 16 + (lane & 15);
    const _Float16* qb = q + (size_t)qrow * 320 + h * 40;
    vh8 a0 = *(const vh8*)(qb + (lane >> 4) * 8);
    vh8 a1 = h8zero();
    if ((lane >> 4) == 0) a1 = *(const vh8*)(qb + 32);
#pragma unroll
    for (int jt = 0; jt < 5; ++jt) {
      int n = jt * 16 + (lane & 15);
      unsigned byte0 = (unsigned)(n * 128 + ((lane >> 4) * 8) * 2) ^ (unsigned)((n & 7) << 4);
      unsigned byte1 = (unsigned)(n * 128 + (32 + (lane >> 4) * 8) * 2) ^ (unsigned)((n & 7) << 4);
      vh8 b0 = *(const vh8*)((const char*)kbuf + byte0);
      vh8 b1 = *(const vh8*)((const char*)kbuf + byte1);
      vf4 s = f4zero();
      s = __builtin_amdgcn_mfma_f32_16x16x32_f16(a0, b0, s, 0, 0, 0);
      s = __builtin_amdgcn_mfma_f32_16x16x32_f16(a1, b1, s, 0, 0, 0);
      if (m2v[n]) {
#pragma unroll
        for (int r = 0; r < 4; ++r) {
          double sv = (double)s[r];
          S += sv; S2 += sv * sv;
        }
      }
    }
  }
  redS[t] = S; redS2[t] = S2;
  __syncthreads();
  for (int off = 128; off > 0; off >>= 1) {
    if (t < off) { redS[t] += redS[t + off]; redS2[t] += redS2[t + off]; }
    __syncthreads();
  }
  if (t == 0) {
    int bid = b * 64 + it;
    partials[2 * bid + 0] = redS[0];
    partials[2 * bid + 1] = redS2[0];
  }
}

__global__ __launch_bounds__(256) void finalize_kernel(
    const double* __restrict__ partials, const int* __restrict__ ctypes,
    float* __restrict__ ssb)
{
  __shared__ double rs[256];
  __shared__ double rs2[256];
  __shared__ int rc[256];
  const int t = threadIdx.x;
  double S = 0.0, S2 = 0.0;
#pragma unroll
  for (int p = 0; p < 4; ++p) {
    int idx = t + p * 256;
    S += partials[2 * idx + 0];
    S2 += partials[2 * idx + 1];
  }
  int c = 0;
#pragma unroll
  for (int p = 0; p < 5; ++p) {
    int idx = t + p * 256;
    if (idx < 1232) c += (ctypes[idx] >= 2) ? 1 : 0;
  }
  rs[t] = S; rs2[t] = S2; rc[t] = c;
  __syncthreads();
  for (int off = 128; off > 0; off >>= 1) {
    if (t < off) { rs[t] += rs[t + off]; rs2[t] += rs2[t + off]; rc[t] += rc[t + off]; }
    __syncthreads();
  }
  if (t == 0) {
    double n = (double)rc[0] * 8.0 * 4096.0;
    double mean = rs[0] / n;
    double var = (rs2[0] - n * mean * mean) / (n - 1.0);
    ssb[0] = (float)sqrt(var > 0.0 ? var : 0.0);
  }
}

// ---------------------------------------------------------------------------
// Fused attention: per (b, 64-row i-tile) x all heads.
// sim MFMA -> LDS, dual masked softmax (4 lanes/row), PV MFMA -> ho fp16.
// ---------------------------------------------------------------------------
__global__ __launch_bounds__(256) void attn_kernel(
    const _Float16* __restrict__ q, const _Float16* __restrict__ kf,
    const _Float16* __restrict__ vf, const float* __restrict__ cam,
    const int* __restrict__ ctypes, const float* __restrict__ pcb,
    const float* __restrict__ ssb, const float* __restrict__ strengthp,
    _Float16* __restrict__ ho)
{
  __shared__ float camsim[64 * 81];        // cam, then reused for sim
  __shared__ _Float16 kbuf[80 * 64];       // [j][d] swizzled
  __shared__ _Float16 vT[48 * 96];         // [d][j] swizzled, pitch 192B
  __shared__ _Float16 attnbuf[64 * 96];    // [row][j] swizzled, pitch 192B
  __shared__ unsigned char lm[64 * 80];    // lmask per (row,j)
  __shared__ unsigned char gmv[96];
  __shared__ unsigned char m2v[96];

  const int t = threadIdx.x, lane = t & 63, wave = t >> 6;
  const int it = blockIdx.x, b = blockIdx.y;
  const int i0 = it * 64;

  if (t < 96) {
    int j = t;
    int ct = (j < 77) ? ctypes[b * 77 + j] : -1;
    gmv[j] = (j < 77 && ct >= 0 && ct < 2) ? 1 : 0;
    m2v[j] = (j < 77 && ct >= 2) ? 1 : 0;
  }
  // stage cam -> camsim[64][81]
#pragma unroll
  for (int p = 0; p < 20; ++p) {
    int idx = t + p * 256;                 // 0..5119
    int row = idx / 80;
    int j = idx - row * 80;
    camsim[row * 81 + j] = (j < 77) ? cam[((size_t)b * 4096 + i0 + row) * 77 + j] : 0.f;
  }
  __syncthreads();

  const float ss = ssb[0];
  const float st = strengthp[0];

  // precompute h-independent lmask
  {
    int row = t >> 2, qd = t & 3;
    float wfv[20];
    float wmax = 0.f, wsum = 0.f;
#pragma unroll
    for (int m = 0; m < 20; ++m) {
      int j = qd + 4 * m;
      float wf = 0.f;
      if (j < 77 && m2v[j]) wf = (camsim[row * 81 + j] * ss) * st;  // ref assoc order
      wfv[m] = wf;
      wmax = fmaxf(wmax, wf);
      wsum += wf;
    }
    wmax = fmaxf(wmax, __shfl_xor(wmax, 1));
    wmax = fmaxf(wmax, __shfl_xor(wmax, 2));
    wsum += __shfl_xor(wsum, 1);
    wsum += __shfl_xor(wsum, 2);
    float thr = fmaxf(wmax, 0.001f) - 0.0001f;
    bool ug = (wsum == 0.f);
#pragma unroll
    for (int m = 0; m < 20; ++m) {
      int j = qd + 4 * m;
      if (j < 80) {
        bool lv = (wfv[m] >= thr) || (ug && gmv[j]);
        lm[row * 80 + j] = lv ? 1 : 0;
      }
    }
  }
  __syncthreads();

  for (int h = 0; h < 8; ++h) {
    // phase A: stage kbuf, zero vT
#pragma unroll
    for (int p = 0; p < 3; ++p) {
      int idx = t + p * 256;
      if (idx < 640) {
        int j = idx >> 3, c8 = idx & 7, d0 = c8 * 8;
        vh8 val = h8zero();
        if (j < 77 && d0 < 40)
          val = *(const vh8*)(kf + (size_t)(b * 77 + j) * 320 + h * 40 + d0);
        unsigned byte = (unsigned)(j * 128 + d0 * 2) ^ (unsigned)((j & 7) << 4);
        *(vh8*)((char*)kbuf + byte) = val;
      }
    }
#pragma unroll
    for (int p = 0; p < 9; ++p) {
      int idx = t + p * 256;                // 2304 dwords = 48*96 halfs
      ((unsigned*)vT)[idx] = 0u;
    }
    __syncthreads();

    // phase B: fill vT (transposed), q frags, sim MFMA, sim -> camsim
#pragma unroll
    for (int p = 0; p < 13; ++p) {
      int idx = t + p * 256;
      if (idx < 3080) {
        int j = idx / 40;
        int d = idx - j * 40;
        _Float16 val = vf[(size_t)(b * 77 + j) * 320 + h * 40 + d];
        unsigned byte = (unsigned)(d * 192 + j * 2) ^ (unsigned)((d & 7) << 4);
        *(_Float16*)((char*)vT + byte) = val;
      }
    }
    {
      int qrow = b * 4096 + i0 + wave * 16 + (lane & 15);
      const _Float16* qb = q + (size_t)qrow * 320 + h * 40;
      vh8 a0 = *(const vh8*)(qb + (lane >> 4) * 8);
      vh8 a1 = h8zero();
      if ((lane >> 4) == 0) a1 = *(const vh8*)(qb + 32);
      vf4 sacc[5];
#pragma unroll
      for (int jt = 0; jt < 5; ++jt) sacc[jt] = f4zero();
#pragma unroll
      for (int jt = 0; jt < 5; ++jt) {
        int n = jt * 16 + (lane & 15);
        unsigned byte0 = (unsigned)(n * 128 + ((lane >> 4) * 8) * 2) ^ (unsigned)((n & 7) << 4);
        unsigned byte1 = (unsigned)(n * 128 + (32 + (lane >> 4) * 8) * 2) ^ (unsigned)((n & 7) << 4);
        vh8 b0 = *(const vh8*)((const char*)kbuf + byte0);
        vh8 b1 = *(const vh8*)((const char*)kbuf + byte1);
        sacc[jt] = __builtin_amdgcn_mfma_f32_16x16x32_f16(a0, b0, sacc[jt], 0, 0, 0);
        sacc[jt] = __builtin_amdgcn_mfma_f32_16x16x32_f16(a1, b1, sacc[jt], 0, 0, 0);
      }
#pragma unroll
      for (int jt = 0; jt < 5; ++jt)
#pragma unroll
        for (int r = 0; r < 4; ++r) {
          int row = wave * 16 + (lane >> 4) * 4 + r;
          int col = jt * 16 + (lane & 15);
          camsim[row * 81 + col] = sacc[jt][r];
        }
    }
    __syncthreads();

    // phase C: dual softmax + combine, write attnbuf
    {
      float pc0 = pcb[(b * 8 + h) * 2 + 0];
      float pc1 = pcb[(b * 8 + h) * 2 + 1];
      int row = t >> 2, qd = t & 3;
      float lgG[20], lgL[20];
      float mg = NEGBIG * SCALE_F, ml = NEGBIG * SCALE_F;
#pragma unroll
      for (int m = 0; m < 20; ++m) {
        int j = qd + 4 * m;
        if (j < 77) {
          float s = camsim[row * 81 + j];
          float gsel = gmv[j] ? s : NEGBIG;
          float lsel = lm[row * 80 + j] ? s : NEGBIG;
          lgG[m] = gsel * SCALE_F;
          lgL[m] = lsel * SCALE_F;
          mg = fmaxf(mg, lgG[m]);
          ml = fmaxf(ml, lgL[m]);
        } else { lgG[m] = NEGBIG; lgL[m] = NEGBIG; }
      }
      mg = fmaxf(mg, __shfl_xor(mg, 1)); mg = fmaxf(mg, __shfl_xor(mg, 2));
      ml = fmaxf(ml, __shfl_xor(ml, 1)); ml = fmaxf(ml, __shfl_xor(ml, 2));
      float sG = 0.f, sL = 0.f;
      float eG[20], eL[20];
#pragma unroll
      for (int m = 0; m < 20; ++m) {
        int j = qd + 4 * m;
        if (j < 77) {
          eG[m] = __expf(lgG[m] - mg);
          eL[m] = __expf(lgL[m] - ml);
          sG += eG[m]; sL += eL[m];
        } else { eG[m] = 0.f; eL[m] = 0.f; }
      }
      sG += __shfl_xor(sG, 1); sG += __shfl_xor(sG, 2);
      sL += __shfl_xor(sL, 1); sL += __shfl_xor(sL, 2);
      float rGc = pc0 / sG, rLc = pc1 / sL;
#pragma unroll
      for (int m = 0; m < 20; ++m) {
        int j = qd + 4 * m;
        float av = (j < 77) ? (eG[m] * rGc + eL[m] * rLc) : 0.f;
        unsigned byte = (unsigned)(row * 192 + j * 2) ^ (unsigned)((row & 7) << 4);
        *(_Float16*)((char*)attnbuf + byte) = (_Float16)av;
      }
#pragma unroll
      for (int m = 20; m < 24; ++m) {
        int j = qd + 4 * m;   // 80..95
        unsigned byte = (unsigned)(row * 192 + j * 2) ^ (unsigned)((row & 7) << 4);
        *(_Float16*)((char*)attnbuf + byte) = (_Float16)0.f;
      }
    }
    __syncthreads();

    // phase D: PV MFMA, store ho
    {
      vf4 oacc[3];
#pragma unroll
      for (int nt = 0; nt < 3; ++nt) oacc[nt] = f4zero();
#pragma unroll
      for (int ks = 0; ks < 3; ++ks) {
        int arow = wave * 16 + (lane & 15);
        unsigned abyte = (unsigned)(arow * 192 + (ks * 32 + (lane >> 4) * 8) * 2) ^ (unsigned)((arow & 7) << 4);
        vh8 pa = *(const vh8*)((const char*)attnbuf + abyte);
#pragma unroll
        for (int nt = 0; nt < 3; ++nt) {
          int n = nt * 16 + (lane & 15);
          unsigned byte = (unsigned)(n * 192 + (ks * 32 + (lane >> 4) * 8) * 2) ^ (unsigned)((n & 7) << 4);
          vh8 vb = *(const vh8*)((const char*)vT + byte);
          oacc[nt] = __builtin_amdgcn_mfma_f32_16x16x32_f16(pa, vb, oacc[nt], 0, 0, 0);
        }
      }
#pragma unroll
      for (int nt = 0; nt < 3; ++nt) {
        int d = nt * 16 + (lane & 15);
        if (d < 40) {
#pragma unroll
          for (int r = 0; r < 4; ++r) {
            int m = wave * 16 + (lane >> 4) * 4 + r;
            ho[(size_t)(b * 4096 + i0 + m) * 320 + h * 40 + d] = (_Float16)oacc[nt][r];
          }
        }
      }
    }
    __syncthreads();
  }
}

// ---------------------------------------------------------------------------
extern "C" void kernel_launch(void* const* d_in, const int* in_sizes, int n_in,
                              void* d_out, int out_size, void* d_ws, size_t ws_size,
                              hipStream_t stream)
{
  const float* x        = (const float*)d_in[0];
  const float* embs     = (const float*)d_in[1];
  const float* cam      = (const float*)d_in[2];
  const float* progress = (const float*)d_in[3];
  const float* strength = (const float*)d_in[4];
  const float* Wq       = (const float*)d_in[5];
  const float* Wk       = (const float*)d_in[6];
  const float* Wv       = (const float*)d_in[7];
  const float* Wo       = (const float*)d_in[8];
  const float* bo       = (const float*)d_in[9];
  const float* emb1     = (const float*)d_in[10];
  const float* emb2     = (const float*)d_in[11];
  const float* Wc1      = (const float*)d_in[12];
  const float* bc1      = (const float*)d_in[13];
  const float* Wc2      = (const float*)d_in[14];
  const float* bc2      = (const float*)d_in[15];
  const int*   ctypes   = (const int*)d_in[16];

  char* w = (char*)d_ws;
  auto alloc = [&](size_t bytes) { char* p = w; w += (bytes + 255) & ~(size_t)255; return p; };
  _Float16* qb   = (_Float16*)alloc(65536ull * 320 * 2);   // 42 MB
  _Float16* kb   = (_Float16*)alloc(1232ull * 320 * 2);
  _Float16* vb   = (_Float16*)alloc(1232ull * 320 * 2);
  _Float16* hob  = (_Float16*)alloc(65536ull * 320 * 2);   // 42 MB
  float*    pcb  = (float*)alloc(256 * 4);
  double*   part = (double*)alloc(1024 * 2 * 8);
  float*    ssb  = (float*)alloc(256);

  classifier_kernel<<<16, 256, 0, stream>>>(progress, emb1, emb2, Wc1, bc1, Wc2, bc2, pcb);
  gemm_kernel<false, false, false><<<dim3(512, 4), 256, 0, stream>>>(x, Wq, nullptr, qb, 65536, 320, 320);
  gemm_kernel<false, false, false><<<dim3(10, 4), 256, 0, stream>>>(embs, Wk, nullptr, kb, 1232, 320, 768);
  gemm_kernel<false, false, false><<<dim3(10, 4), 256, 0, stream>>>(embs, Wv, nullptr, vb, 1232, 320, 768);
  std_kernel<<<dim3(64, 16), 256, 0, stream>>>(qb, kb, ctypes, part);
  finalize_kernel<<<1, 256, 0, stream>>>(part, ctypes, ssb);
  attn_kernel<<<dim3(64, 16), 256, 0, stream>>>(qb, kb, vb, cam, ctypes, pcb, ssb, strength, hob);
  gemm_kernel<true, true, true><<<dim3(512, 4), 256, 0, stream>>>(hob, Wo, bo, (float*)d_out, 65536, 320, 320);
}

// Round 2
// 320.750 us; speedup vs baseline: 1.5942x; 1.5942x over previous
//
#include <hip/hip_runtime.h>

// ---------------------------------------------------------------------------
// CustomCrossAttentionMinimal on MI355X (gfx950)
// b=16, i=4096, j=77, qd=320, cd=768, H=8, DH=40, inner=320
// ---------------------------------------------------------------------------

typedef _Float16 vh8 __attribute__((ext_vector_type(8)));
typedef _Float16 vh4 __attribute__((ext_vector_type(4)));
typedef float    vf4 __attribute__((ext_vector_type(4)));

#define NEGBIG  (-3.4028235e38f)
#define SCALE_F 0.15811388300841897f   // 40^-0.5
#define NEGS    (-5.380458e37f)        // NEGBIG * SCALE_F (fp32)

__device__ __forceinline__ vh8 h8zero() {
  vh8 v;
#pragma unroll
  for (int i = 0; i < 8; ++i) v[i] = (_Float16)0.f;
  return v;
}
__device__ __forceinline__ vf4 f4zero() {
  vf4 v;
#pragma unroll
  for (int i = 0; i < 4; ++i) v[i] = 0.f;
  return v;
}
__device__ __forceinline__ float gelu_exact(float x) {
  return 0.5f * x * (1.0f + erff(x * 0.70710678118654752f));
}

// ---------------------------------------------------------------------------
// Weight pre-transpose to fp16 [N][K]:
//  WqT[320][320], WkvT[640][768] (rows 0..319 = Wk^T, 320..639 = Wv^T), WoT[320][320]
// ---------------------------------------------------------------------------
__global__ __launch_bounds__(256) void transpose_kernel(
    const float* __restrict__ Wq, const float* __restrict__ Wk,
    const float* __restrict__ Wv, const float* __restrict__ Wo,
    _Float16* __restrict__ WqT, _Float16* __restrict__ WkvT, _Float16* __restrict__ WoT)
{
  int idx = blockIdx.x * 256 + threadIdx.x;
  if (idx < 102400) {
    int n = idx / 320, k = idx - n * 320;
    WqT[idx] = (_Float16)Wq[k * 320 + n];
    return;
  }
  idx -= 102400;
  if (idx < 491520) {
    int n = idx / 768, k = idx - n * 768;
    float v = (n < 320) ? Wk[k * 320 + n] : Wv[k * 320 + (n - 320)];
    WkvT[idx] = (_Float16)v;
    return;
  }
  idx -= 491520;
  if (idx < 102400) {
    int n = idx / 320, k = idx - n * 320;
    WoT[idx] = (_Float16)Wo[k * 320 + n];
  }
}

// ---------------------------------------------------------------------------
// fp16-MFMA GEMM:  C[M,N] = A[M,K] @ Bt[N,K]^T (+bias)
// A fp32 or fp16 row-major; Bt fp16 [N][K]; BM=128, BN=80, BK=64, 4 waves.
// ---------------------------------------------------------------------------
template<bool A_HALF, bool BIAS, bool OUT_F32>
__global__ __launch_bounds__(256) void gemm_kernel(
    const void* __restrict__ Ap, const _Float16* __restrict__ Bt,
    const float* __restrict__ bias, void* __restrict__ Cp,
    int M, int N, int K)
{
  __shared__ _Float16 As[128 * 64];   // [row][k], pitch 128B, XOR (row&7)<<4
  __shared__ _Float16 Bs[80 * 64];    // [n][k],  pitch 128B, XOR (n&7)<<4
  const int t    = threadIdx.x;
  const int lane = t & 63;
  const int wave = t >> 6;
  const int m0 = blockIdx.x * 128;
  const int n0 = blockIdx.y * 80;
  const int l15 = lane & 15, l4 = lane >> 4;

  vf4 acc[2][5];
#pragma unroll
  for (int a = 0; a < 2; ++a)
#pragma unroll
    for (int bq = 0; bq < 5; ++bq) acc[a][bq] = f4zero();

  for (int k0 = 0; k0 < K; k0 += 64) {
    __syncthreads();
    if (A_HALF) {
#pragma unroll
      for (int p = 0; p < 4; ++p) {
        int idx = t + p * 256;          // 0..1023
        int row = idx >> 3, c8 = idx & 7;
        int m = m0 + row;
        vh8 hv = h8zero();
        if (m < M) hv = *(const vh8*)((const _Float16*)Ap + (size_t)m * K + k0 + c8 * 8);
        unsigned byte = (unsigned)(row * 128 + c8 * 16) ^ (unsigned)((row & 7) << 4);
        *(vh8*)((char*)As + byte) = hv;
      }
    } else {
#pragma unroll
      for (int p = 0; p < 8; ++p) {
        int idx = t + p * 256;          // 0..2047
        int row = idx >> 4, g4 = idx & 15;
        int m = m0 + row;
        vh4 hw;
        hw[0] = (_Float16)0.f; hw[1] = (_Float16)0.f; hw[2] = (_Float16)0.f; hw[3] = (_Float16)0.f;
        if (m < M) {
          const float* ap = (const float*)Ap + (size_t)m * K + k0 + g4 * 4;
          float4 f = *(const float4*)ap;
          hw[0] = (_Float16)f.x; hw[1] = (_Float16)f.y; hw[2] = (_Float16)f.z; hw[3] = (_Float16)f.w;
        }
        unsigned byte = (unsigned)(row * 128 + g4 * 8) ^ (unsigned)((row & 7) << 4);
        *(vh4*)((char*)As + byte) = hw;
      }
    }
    // B tile: 80 n-rows x 64 k, vectorized
#pragma unroll
    for (int p = 0; p < 3; ++p) {
      int idx = t + p * 256;            // 0..767
      if (idx < 640) {
        int n = idx >> 3, c8 = idx & 7;
        vh8 bvv = *(const vh8*)(Bt + (size_t)(n0 + n) * K + k0 + c8 * 8);
        unsigned byte = (unsigned)(n * 128 + c8 * 16) ^ (unsigned)((n & 7) << 4);
        *(vh8*)((char*)Bs + byte) = bvv;
      }
    }
    __syncthreads();
#pragma unroll
    for (int ks = 0; ks < 2; ++ks) {
      vh8 av[2], bv[5];
#pragma unroll
      for (int mt = 0; mt < 2; ++mt) {
        int row = wave * 32 + mt * 16 + l15;
        unsigned byte = (unsigned)(row * 128 + (ks * 32 + l4 * 8) * 2) ^ (unsigned)((row & 7) << 4);
        av[mt] = *(const vh8*)((const char*)As + byte);
      }
#pragma unroll
      for (int nt = 0; nt < 5; ++nt) {
        int n = nt * 16 + l15;
        unsigned byte = (unsigned)(n * 128 + (ks * 32 + l4 * 8) * 2) ^ (unsigned)((n & 7) << 4);
        bv[nt] = *(const vh8*)((const char*)Bs + byte);
      }
#pragma unroll
      for (int mt = 0; mt < 2; ++mt)
#pragma unroll
        for (int nt = 0; nt < 5; ++nt)
          acc[mt][nt] = __builtin_amdgcn_mfma_f32_16x16x32_f16(av[mt], bv[nt], acc[mt][nt], 0, 0, 0);
    }
  }
#pragma unroll
  for (int mt = 0; mt < 2; ++mt)
#pragma unroll
    for (int nt = 0; nt < 5; ++nt) {
      int n = n0 + nt * 16 + l15;
#pragma unroll
      for (int r = 0; r < 4; ++r) {
        int m = m0 + wave * 32 + mt * 16 + l4 * 4 + r;
        if (m < M) {
          float v = acc[mt][nt][r];
          if (BIAS) v += bias[n];
          if (OUT_F32) ((float*)Cp)[(size_t)m * N + n] = v;
          else ((_Float16*)Cp)[(size_t)m * N + n] = (_Float16)v;
        }
      }
    }
}

// ---------------------------------------------------------------------------
// Progress classifier
// ---------------------------------------------------------------------------
__global__ __launch_bounds__(256) void classifier_kernel(
    const float* __restrict__ progress,
    const float* __restrict__ emb1, const float* __restrict__ emb2,
    const float* __restrict__ Wc1, const float* __restrict__ bc1,
    const float* __restrict__ Wc2, const float* __restrict__ bc2,
    float* __restrict__ pcb)
{
  __shared__ float g[512];
  __shared__ float h1[512];
  __shared__ float lg[16];
  const int b = blockIdx.x;
  const int t = threadIdx.x;

  float pr = progress[b];
  int xstep = (int)rintf(pr * 1000.0f);
  if (xstep > 999) xstep = 999;
  int a = xstep / 20;
  int r = xstep - a * 20;

  for (int d = t; d < 512; d += 256) {
    float e = emb1[a * 512 + d] + emb2[r * 512 + d];
    g[d] = gelu_exact(e);
  }
  __syncthreads();
  for (int n = t; n < 512; n += 256) {
    float acc = bc1[n];
    for (int d = 0; d < 512; ++d) acc = fmaf(g[d], Wc1[d * 512 + n], acc);
    h1[n] = gelu_exact(acc);
  }
  __syncthreads();
  if (t < 16) {
    float acc = bc2[t];
    for (int d = 0; d < 512; ++d) acc = fmaf(h1[d], Wc2[d * 16 + t], acc);
    lg[t] = acc;
  }
  __syncthreads();
  if (t < 8) {
    float a0 = lg[2 * t], a1 = lg[2 * t + 1];
    float mx = fmaxf(a0, a1);
    float e0 = __expf(a0 - mx), e1 = __expf(a1 - mx);
    float inv = 1.0f / (e0 + e1);
    pcb[(b * 8 + t) * 2 + 0] = e0 * inv;
    pcb[(b * 8 + t) * 2 + 1] = e1 * inv;
  }
}

// ---------------------------------------------------------------------------
// Masked Sum/SumSq of sim (fp64 partials). Grid (64 itiles, 16 b, 8 h).
// ---------------------------------------------------------------------------
__global__ __launch_bounds__(256) void std_kernel(
    const _Float16* __restrict__ q, const _Float16* __restrict__ kf,
    const int* __restrict__ ctypes, double* __restrict__ partials)
{
  __shared__ _Float16 kbuf[80 * 64];
  __shared__ unsigned char m2v[96];
  __shared__ double redS[256];
  __shared__ double redS2[256];
  const int t = threadIdx.x, lane = t & 63, wave = t >> 6;
  const int it = blockIdx.x, b = blockIdx.y, h = blockIdx.z;
  const int i0 = it * 64;
  const int l15 = lane & 15, l4 = lane >> 4;

  if (t < 96) {
    int j = t;
    int ct = (j < 77) ? ctypes[b * 77 + j] : -1;
    m2v[j] = (j < 77 && ct >= 2) ? 1 : 0;
  }
#pragma unroll
  for (int p = 0; p < 3; ++p) {
    int idx = t + p * 256;
    if (idx < 640) {
      int j = idx >> 3, c8 = idx & 7, d0 = c8 * 8;
      vh8 val = h8zero();
      if (j < 77 && d0 < 40)
        val = *(const vh8*)(kf + (size_t)(b * 77 + j) * 640 + h * 40 + d0);
      unsigned byte = (unsigned)(j * 128 + d0 * 2) ^ (unsigned)((j & 7) << 4);
      *(vh8*)((char*)kbuf + byte) = val;
    }
  }
  __syncthreads();

  int qrow = b * 4096 + i0 + wave * 16 + l15;
  const _Float16* qb = q + (size_t)qrow * 320 + h * 40;
  vh8 a0 = *(const vh8*)(qb + l4 * 8);
  vh8 a1 = h8zero();
  if (l4 == 0) a1 = *(const vh8*)(qb + 32);

  double S = 0.0, S2 = 0.0;
#pragma unroll
  for (int jt = 0; jt < 5; ++jt) {
    int n = jt * 16 + l15;
    unsigned byte0 = (unsigned)(n * 128 + (l4 * 8) * 2) ^ (unsigned)((n & 7) << 4);
    unsigned byte1 = (unsigned)(n * 128 + (32 + l4 * 8) * 2) ^ (unsigned)((n & 7) << 4);
    vh8 b0 = *(const vh8*)((const char*)kbuf + byte0);
    vh8 b1 = *(const vh8*)((const char*)kbuf + byte1);
    vf4 s = f4zero();
    s = __builtin_amdgcn_mfma_f32_16x16x32_f16(a0, b0, s, 0, 0, 0);
    s = __builtin_amdgcn_mfma_f32_16x16x32_f16(a1, b1, s, 0, 0, 0);
    if (m2v[n]) {
#pragma unroll
      for (int r = 0; r < 4; ++r) {
        double sv = (double)s[r];
        S += sv; S2 += sv * sv;
      }
    }
  }
  redS[t] = S; redS2[t] = S2;
  __syncthreads();
  for (int off = 128; off > 0; off >>= 1) {
    if (t < off) { redS[t] += redS[t + off]; redS2[t] += redS2[t + off]; }
    __syncthreads();
  }
  if (t == 0) {
    int bid = (b * 64 + it) * 8 + h;
    partials[2 * bid + 0] = redS[0];
    partials[2 * bid + 1] = redS2[0];
  }
}

__global__ __launch_bounds__(256) void finalize_kernel(
    const double* __restrict__ partials, const int* __restrict__ ctypes,
    float* __restrict__ ssb)
{
  __shared__ double rs[256];
  __shared__ double rs2[256];
  __shared__ int rc[256];
  const int t = threadIdx.x;
  double S = 0.0, S2 = 0.0;
#pragma unroll
  for (int p = 0; p < 32; ++p) {
    int idx = t + p * 256;
    S += partials[2 * idx + 0];
    S2 += partials[2 * idx + 1];
  }
  int c = 0;
#pragma unroll
  for (int p = 0; p < 5; ++p) {
    int idx = t + p * 256;
    if (idx < 1232) c += (ctypes[idx] >= 2) ? 1 : 0;
  }
  rs[t] = S; rs2[t] = S2; rc[t] = c;
  __syncthreads();
  for (int off = 128; off > 0; off >>= 1) {
    if (t < off) { rs[t] += rs[t + off]; rs2[t] += rs2[t + off]; rc[t] += rc[t + off]; }
    __syncthreads();
  }
  if (t == 0) {
    double n = (double)rc[0] * 8.0 * 4096.0;
    double mean = rs[0] / n;
    double var = (rs2[0] - n * mean * mean) / (n - 1.0);
    ssb[0] = (float)sqrt(var > 0.0 ? var : 0.0);
  }
}

// ---------------------------------------------------------------------------
// lmask precompute: packed bits lmp[row][qd], qd=j&3, bit m=j>>2.
// Grid (64 itiles, 16 b), 256 thr (4 lanes per row).
// ---------------------------------------------------------------------------
__global__ __launch_bounds__(256) void lmask_kernel(
    const float* __restrict__ cam, const int* __restrict__ ctypes,
    const float* __restrict__ ssb, const float* __restrict__ strengthp,
    unsigned* __restrict__ lmp)
{
  __shared__ float camt[64 * 81];
  __shared__ unsigned char gmv[96];
  __shared__ unsigned char m2v[96];
  const int t = threadIdx.x;
  const int it = blockIdx.x, b = blockIdx.y;
  const int i0 = it * 64;

  if (t < 96) {
    int j = t;
    int ct = (j < 77) ? ctypes[b * 77 + j] : -1;
    gmv[j] = (j < 77 && ct >= 0 && ct < 2) ? 1 : 0;
    m2v[j] = (j < 77 && ct >= 2) ? 1 : 0;
  }
#pragma unroll
  for (int p = 0; p < 20; ++p) {
    int idx = t + p * 256;                 // 0..5119
    int row = idx / 80;
    int j = idx - row * 80;
    camt[row * 81 + j] = (j < 77) ? cam[((size_t)b * 4096 + i0 + row) * 77 + j] : 0.f;
  }
  __syncthreads();

  const float ss = ssb[0];
  const float st = strengthp[0];
  int row = t >> 2, qd = t & 3;
  float wfv[20];
  float wmax = 0.f, wsum = 0.f;
#pragma unroll
  for (int m = 0; m < 20; ++m) {
    int j = qd + 4 * m;
    float wf = 0.f;
    if (j < 77 && m2v[j]) wf = (camt[row * 81 + j] * ss) * st;   // ref assoc order
    wfv[m] = wf;
    wmax = fmaxf(wmax, wf);
    wsum += wf;
  }
  wmax = fmaxf(wmax, __shfl_xor(wmax, 1));
  wmax = fmaxf(wmax, __shfl_xor(wmax, 2));
  wsum += __shfl_xor(wsum, 1);
  wsum += __shfl_xor(wsum, 2);
  float thr = fmaxf(wmax, 0.001f) - 0.0001f;
  bool ug = (wsum == 0.f);
  unsigned wbits = 0u;
#pragma unroll
  for (int m = 0; m < 20; ++m) {
    int j = qd + 4 * m;
    bool lv = (wfv[m] >= thr) || (ug && (j < 77) && gmv[j]);
    if (lv) wbits |= (1u << m);
  }
  lmp[((size_t)b * 4096 + i0 + row) * 4 + qd] = wbits;
}

// ---------------------------------------------------------------------------
// Fused attention: grid (64 itiles, 16 b, 8 h), 256 thr, in-fragment softmax.
// ---------------------------------------------------------------------------
__global__ __launch_bounds__(256) void attn_kernel(
    const _Float16* __restrict__ q, const _Float16* __restrict__ kf,
    const _Float16* __restrict__ vf, const int* __restrict__ ctypes,
    const float* __restrict__ pcb, const unsigned* __restrict__ lmp,
    _Float16* __restrict__ ho)
{
  __shared__ _Float16 kbuf[80 * 64];       // [j][d] pitch 128B, XOR (j&7)<<4
  __shared__ _Float16 vT[48 * 128];        // [d][j] pitch 256B, XOR (d&7)<<4
  __shared__ _Float16 attnbuf[64 * 128];   // [row][j] pitch 256B, XOR (row&7)<<4
  __shared__ unsigned lmw[256];            // packed lmask, [row][qd]
  __shared__ unsigned char gmv[96];

  const int t = threadIdx.x, lane = t & 63, wave = t >> 6;
  const int it = blockIdx.x, b = blockIdx.y, h = blockIdx.z;
  const int i0 = it * 64;
  const int l15 = lane & 15, l4 = lane >> 4;

  if (t < 96) {
    int j = t;
    int ct = (j < 77) ? ctypes[b * 77 + j] : -1;
    gmv[j] = (j < 77 && ct >= 0 && ct < 2) ? 1 : 0;
  }
  lmw[t] = lmp[((size_t)b * 4096 + i0) * 4 + t];

  // K tile
#pragma unroll
  for (int p = 0; p < 3; ++p) {
    int idx = t + p * 256;
    if (idx < 640) {
      int j = idx >> 3, c8 = idx & 7, d0 = c8 * 8;
      vh8 val = h8zero();
      if (j < 77 && d0 < 40)
        val = *(const vh8*)(kf + (size_t)(b * 77 + j) * 640 + h * 40 + d0);
      unsigned byte = (unsigned)(j * 128 + d0 * 2) ^ (unsigned)((j & 7) << 4);
      *(vh8*)((char*)kbuf + byte) = val;
    }
  }
  // zero vT (48*128 halfs = 3072 u32)
#pragma unroll
  for (int p = 0; p < 12; ++p) ((unsigned*)vT)[t + p * 256] = 0u;
  // zero attnbuf j in [80,96): 64 rows x 8 u32
#pragma unroll
  for (int p = 0; p < 2; ++p) {
    int idx = t + p * 256;                 // 0..511
    int row = idx >> 3, c = idx & 7;
    unsigned byte = (unsigned)(row * 256 + 160 + c * 4) ^ (unsigned)((row & 7) << 4);
    *(unsigned*)((char*)attnbuf + byte) = 0u;
  }
  __syncthreads();
  // fill vT transposed (after zero-pass barrier to avoid overwrite hazards)
#pragma unroll
  for (int p = 0; p < 13; ++p) {
    int idx = t + p * 256;
    if (idx < 3080) {
      int j = idx / 40;
      int d = idx - j * 40;
      _Float16 val = vf[(size_t)(b * 77 + j) * 640 + h * 40 + d];
      unsigned byte = (unsigned)(d * 256 + j * 2) ^ (unsigned)((d & 7) << 4);
      *(_Float16*)((char*)vT + byte) = val;
    }
  }

  // Q frags + sim MFMA (registers only)
  int qrow = b * 4096 + i0 + wave * 16 + l15;
  const _Float16* qbp = q + (size_t)qrow * 320 + h * 40;
  vh8 a0 = *(const vh8*)(qbp + l4 * 8);
  vh8 a1 = h8zero();
  if (l4 == 0) a1 = *(const vh8*)(qbp + 32);

  __syncthreads();   // kbuf + vT + lmw ready

  vf4 sacc[5];
#pragma unroll
  for (int jt = 0; jt < 5; ++jt) sacc[jt] = f4zero();
#pragma unroll
  for (int jt = 0; jt < 5; ++jt) {
    int n = jt * 16 + l15;
    unsigned byte0 = (unsigned)(n * 128 + (l4 * 8) * 2) ^ (unsigned)((n & 7) << 4);
    unsigned byte1 = (unsigned)(n * 128 + (32 + l4 * 8) * 2) ^ (unsigned)((n & 7) << 4);
    vh8 b0 = *(const vh8*)((const char*)kbuf + byte0);
    vh8 b1 = *(const vh8*)((const char*)kbuf + byte1);
    sacc[jt] = __builtin_amdgcn_mfma_f32_16x16x32_f16(a0, b0, sacc[jt], 0, 0, 0);
    sacc[jt] = __builtin_amdgcn_mfma_f32_16x16x32_f16(a1, b1, sacc[jt], 0, 0, 0);
  }

  // in-fragment dual softmax; write combined attn to attnbuf
  const float pc0 = pcb[(b * 8 + h) * 2 + 0];
  const float pc1 = pcb[(b * 8 + h) * 2 + 1];
  const int bitbase = (lane >> 2) & 3;
#pragma unroll
  for (int r = 0; r < 4; ++r) {
    int row = wave * 16 + l4 * 4 + r;
    unsigned wbits = lmw[row * 4 + (lane & 3)];
    float gv[5], lv[5];
    float mg = -3.0e38f, ml = -3.0e38f;
#pragma unroll
    for (int jt = 0; jt < 5; ++jt) {
      int j = jt * 16 + l15;
      float s = sacc[jt][r] * SCALE_F;
      bool valid = (j < 77);
      bool gm = valid && gmv[j];
      bool lb = valid && ((wbits >> (jt * 4 + bitbase)) & 1u);
      gv[jt] = valid ? (gm ? s : NEGS) : -__builtin_inff();
      lv[jt] = valid ? (lb ? s : NEGS) : -__builtin_inff();
      mg = fmaxf(mg, gv[jt]);
      ml = fmaxf(ml, lv[jt]);
    }
    mg = fmaxf(mg, __shfl_xor(mg, 1)); mg = fmaxf(mg, __shfl_xor(mg, 2));
    mg = fmaxf(mg, __shfl_xor(mg, 4)); mg = fmaxf(mg, __shfl_xor(mg, 8));
    ml = fmaxf(ml, __shfl_xor(ml, 1)); ml = fmaxf(ml, __shfl_xor(ml, 2));
    ml = fmaxf(ml, __shfl_xor(ml, 4)); ml = fmaxf(ml, __shfl_xor(ml, 8));
    float eG[5], eL[5];
    float sG = 0.f, sL = 0.f;
#pragma unroll
    for (int jt = 0; jt < 5; ++jt) {
      eG[jt] = __expf(gv[jt] - mg);
      eL[jt] = __expf(lv[jt] - ml);
      sG += eG[jt]; sL += eL[jt];
    }
    sG += __shfl_xor(sG, 1); sG += __shfl_xor(sG, 2);
    sG += __shfl_xor(sG, 4); sG += __shfl_xor(sG, 8);
    sL += __shfl_xor(sL, 1); sL += __shfl_xor(sL, 2);
    sL += __shfl_xor(sL, 4); sL += __shfl_xor(sL, 8);
    float rG = pc0 / sG, rL = pc1 / sL;
#pragma unroll
    for (int jt = 0; jt < 5; ++jt) {
      int j = jt * 16 + l15;
      float av = eG[jt] * rG + eL[jt] * rL;
      unsigned byte = (unsigned)(row * 256 + j * 2) ^ (unsigned)((row & 7) << 4);
      *(_Float16*)((char*)attnbuf + byte) = (_Float16)av;
    }
  }
  __syncthreads();

  // PV MFMA, store ho
  vf4 oacc[3];
#pragma unroll
  for (int nt = 0; nt < 3; ++nt) oacc[nt] = f4zero();
#pragma unroll
  for (int ks = 0; ks < 3; ++ks) {
    int arow = wave * 16 + l15;
    unsigned abyte = (unsigned)(arow * 256 + (ks * 32 + l4 * 8) * 2) ^ (unsigned)((arow & 7) << 4);
    vh8 pa = *(const vh8*)((const char*)attnbuf + abyte);
#pragma unroll
    for (int nt = 0; nt < 3; ++nt) {
      int n = nt * 16 + l15;
      unsigned byte = (unsigned)(n * 256 + (ks * 32 + l4 * 8) * 2) ^ (unsigned)((n & 7) << 4);
      vh8 vb = *(const vh8*)((const char*)vT + byte);
      oacc[nt] = __builtin_amdgcn_mfma_f32_16x16x32_f16(pa, vb, oacc[nt], 0, 0, 0);
    }
  }
#pragma unroll
  for (int nt = 0; nt < 3; ++nt) {
    int d = nt * 16 + l15;
    if (d < 40) {
#pragma unroll
      for (int r = 0; r < 4; ++r) {
        int m = wave * 16 + l4 * 4 + r;
        ho[(size_t)(b * 4096 + i0 + m) * 320 + h * 40 + d] = (_Float16)oacc[nt][r];
      }
    }
  }
}

// ---------------------------------------------------------------------------
extern "C" void kernel_launch(void* const* d_in, const int* in_sizes, int n_in,
                              void* d_out, int out_size, void* d_ws, size_t ws_size,
                              hipStream_t stream)
{
  const float* x        = (const float*)d_in[0];
  const float* embs     = (const float*)d_in[1];
  const float* cam      = (const float*)d_in[2];
  const float* progress = (const float*)d_in[3];
  const float* strength = (const float*)d_in[4];
  const float* Wq       = (const float*)d_in[5];
  const float* Wk       = (const float*)d_in[6];
  const float* Wv       = (const float*)d_in[7];
  const float* Wo       = (const float*)d_in[8];
  const float* bo       = (const float*)d_in[9];
  const float* emb1     = (const float*)d_in[10];
  const float* emb2     = (const float*)d_in[11];
  const float* Wc1      = (const float*)d_in[12];
  const float* bc1      = (const float*)d_in[13];
  const float* Wc2      = (const float*)d_in[14];
  const float* bc2      = (const float*)d_in[15];
  const int*   ctypes   = (const int*)d_in[16];

  char* w = (char*)d_ws;
  auto alloc = [&](size_t bytes) { char* p = w; w += (bytes + 255) & ~(size_t)255; return p; };
  _Float16* qb    = (_Float16*)alloc(65536ull * 320 * 2);   // 40 MiB
  _Float16* hob   = (_Float16*)alloc(65536ull * 320 * 2);   // 40 MiB
  _Float16* kvb   = (_Float16*)alloc(1232ull * 640 * 2);    // 1.5 MiB
  _Float16* WqT   = (_Float16*)alloc(320ull * 320 * 2);
  _Float16* WkvT  = (_Float16*)alloc(640ull * 768 * 2);
  _Float16* WoT   = (_Float16*)alloc(320ull * 320 * 2);
  unsigned* lmp   = (unsigned*)alloc(65536ull * 4 * 4);     // 1 MiB
  float*    pcb   = (float*)alloc(256 * 4);
  double*   part  = (double*)alloc(8192ull * 2 * 8);
  float*    ssb   = (float*)alloc(256);

  transpose_kernel<<<2720, 256, 0, stream>>>(Wq, Wk, Wv, Wo, WqT, WkvT, WoT);
  classifier_kernel<<<16, 256, 0, stream>>>(progress, emb1, emb2, Wc1, bc1, Wc2, bc2, pcb);
  gemm_kernel<false, false, false><<<dim3(512, 4), 256, 0, stream>>>(x, WqT, nullptr, qb, 65536, 320, 320);
  gemm_kernel<false, false, false><<<dim3(10, 8), 256, 0, stream>>>(embs, WkvT, nullptr, kvb, 1232, 640, 768);
  std_kernel<<<dim3(64, 16, 8), 256, 0, stream>>>(qb, kvb, ctypes, part);
  finalize_kernel<<<1, 256, 0, stream>>>(part, ctypes, ssb);
  lmask_kernel<<<dim3(64, 16), 256, 0, stream>>>(cam, ctypes, ssb, strength, lmp);
  attn_kernel<<<dim3(64, 16, 8), 256, 0, stream>>>(qb, kvb, kvb + 320, ctypes, pcb, lmp, hob);
  gemm_kernel<true, true, true><<<dim3(512, 4), 256, 0, stream>>>(hob, WoT, bo, (float*)d_out, 65536, 320, 320);
}